// Round 1
// baseline (170.710 us; speedup 1.0000x reference)
//
#include <hip/hip_runtime.h>

// Gaussian mixture field evaluation:
//   out[m] = sum_n I_n * exp(-0.5 * (x_m - mu_n)^T A_n (x_m - mu_n))
// expanded as q = x^T A x - 2 x^T b + c with per-gaussian precomputed
// coefficients, folded with K = -0.5*log2(e) so exp(-q/2) = exp2(dot).

#define M_POINTS 65536
#define N_GAUSS  4096
#define KNEG     (-0.72134752044448170f)   // -0.5 * log2(e)

// ---------------------------------------------------------------------------
// Kernel 1: per-gaussian coefficient precompute (4096 threads, ~2 us)
// layout per gaussian (12 floats = 3 x float4):
//   [0..2]  K*a00, K*a11, K*a22
//   [3..5]  2K*a01, 2K*a02, 2K*a12
//   [6..8]  -2K*b0, -2K*b1, -2K*b2
//   [9]     K*c
//   [10]    intensity
//   [11]    pad
// ---------------------------------------------------------------------------
__global__ __launch_bounds__(256) void precompute_coeffs(
    const float* __restrict__ pos, const float* __restrict__ scl,
    const float* __restrict__ rot, const float* __restrict__ inten,
    float* __restrict__ coef)
{
    int n = blockIdx.x * blockDim.x + threadIdx.x;
    if (n >= N_GAUSS) return;

    float qw = rot[4*n+0], qx = rot[4*n+1], qy = rot[4*n+2], qz = rot[4*n+3];
    float nrm = sqrtf(qw*qw + qx*qx + qy*qy + qz*qz) + 1e-8f;
    float ir = 1.0f / nrm;
    qw *= ir; qx *= ir; qy *= ir; qz *= ir;

    float r00 = 1.f - 2.f*(qy*qy + qz*qz);
    float r01 = 2.f*(qx*qy - qz*qw);
    float r02 = 2.f*(qx*qz + qy*qw);
    float r10 = 2.f*(qx*qy + qz*qw);
    float r11 = 1.f - 2.f*(qx*qx + qz*qz);
    float r12 = 2.f*(qy*qz - qx*qw);
    float r20 = 2.f*(qx*qz - qy*qw);
    float r21 = 2.f*(qy*qz + qx*qw);
    float r22 = 1.f - 2.f*(qx*qx + qy*qy);

    float s0 = fabsf(scl[3*n+0]) + 1e-6f;
    float s1 = fabsf(scl[3*n+1]) + 1e-6f;
    float s2 = fabsf(scl[3*n+2]) + 1e-6f;
    float w0 = 1.f/(s0*s0), w1 = 1.f/(s1*s1), w2 = 1.f/(s2*s2);

    // A = R diag(w) R^T  (symmetric)
    float a00 = r00*r00*w0 + r01*r01*w1 + r02*r02*w2;
    float a01 = r00*r10*w0 + r01*r11*w1 + r02*r12*w2;
    float a02 = r00*r20*w0 + r01*r21*w1 + r02*r22*w2;
    float a11 = r10*r10*w0 + r11*r11*w1 + r12*r12*w2;
    float a12 = r10*r20*w0 + r11*r21*w1 + r12*r22*w2;
    float a22 = r20*r20*w0 + r21*r21*w1 + r22*r22*w2;

    float p0 = pos[3*n+0], p1 = pos[3*n+1], p2 = pos[3*n+2];
    float b0 = a00*p0 + a01*p1 + a02*p2;
    float b1 = a01*p0 + a11*p1 + a12*p2;
    float b2 = a02*p0 + a12*p1 + a22*p2;
    float c  = b0*p0 + b1*p1 + b2*p2;

    float* o = coef + 12*n;
    o[0]  = KNEG * a00;
    o[1]  = KNEG * a11;
    o[2]  = KNEG * a22;
    o[3]  = 2.f * KNEG * a01;
    o[4]  = 2.f * KNEG * a02;
    o[5]  = 2.f * KNEG * a12;
    o[6]  = -2.f * KNEG * b0;
    o[7]  = -2.f * KNEG * b1;
    o[8]  = -2.f * KNEG * b2;
    o[9]  = KNEG * c;
    o[10] = inten[n];
    o[11] = 0.f;
}

__device__ __forceinline__ float fast_exp2(float x) {
#if defined(__has_builtin)
#if __has_builtin(__builtin_amdgcn_exp2f)
    return __builtin_amdgcn_exp2f(x);   // raw v_exp_f32
#else
    return exp2f(x);
#endif
#else
    return exp2f(x);
#endif
}

// ---------------------------------------------------------------------------
// Kernel 2: main evaluation.
// grid(128, 8): blockIdx.x selects a 512-point slab, blockIdx.y selects a
// 512-gaussian chunk. 2 points/thread (ILP-2 over the 9-deep FMA chain).
// Coefficient loads are wave-uniform -> scalar loads (s_load_dwordx4),
// zero pressure on the vector-memory / LDS pipes. Partials combined with
// atomicAdd (8 adds per output element, negligible contention).
// ---------------------------------------------------------------------------
#define PT_BLOCKS 128      // 65536 / (256 threads * 2 pts)
#define G_SPLIT   8
#define G_CHUNK   (N_GAUSS / G_SPLIT)   // 512

__global__ __launch_bounds__(256) void gauss_eval(
    const float*  __restrict__ pts,
    const float4* __restrict__ coef,   // 3 x float4 per gaussian
    float*        __restrict__ out)
{
    const int t  = threadIdx.x;
    const int i0 = blockIdx.x * 512 + t;
    const int i1 = i0 + 256;

    const float x0 = pts[3*i0+0], y0 = pts[3*i0+1], z0 = pts[3*i0+2];
    const float x1 = pts[3*i1+0], y1 = pts[3*i1+1], z1 = pts[3*i1+2];

    // per-point monomials
    const float xx0 = x0*x0, yy0 = y0*y0, zz0 = z0*z0;
    const float xy0 = x0*y0, xz0 = x0*z0, yz0 = y0*z0;
    const float xx1 = x1*x1, yy1 = y1*y1, zz1 = z1*z1;
    const float xy1 = x1*y1, xz1 = x1*z1, yz1 = y1*z1;

    float sum0 = 0.f, sum1 = 0.f;

    const int nbeg = blockIdx.y * G_CHUNK;
    const int nend = nbeg + G_CHUNK;

#pragma unroll 4
    for (int n = nbeg; n < nend; ++n) {
        const float4 c0 = coef[3*n + 0];  // Ka00 Ka11 Ka22 2Ka01
        const float4 c1 = coef[3*n + 1];  // 2Ka02 2Ka12 f0 f1
        const float4 c2 = coef[3*n + 2];  // f2 Kc I pad

        float t0 = c2.y;
        t0 = fmaf(c0.x, xx0, t0);
        t0 = fmaf(c0.y, yy0, t0);
        t0 = fmaf(c0.z, zz0, t0);
        t0 = fmaf(c0.w, xy0, t0);
        t0 = fmaf(c1.x, xz0, t0);
        t0 = fmaf(c1.y, yz0, t0);
        t0 = fmaf(c1.z, x0,  t0);
        t0 = fmaf(c1.w, y0,  t0);
        t0 = fmaf(c2.x, z0,  t0);

        float t1 = c2.y;
        t1 = fmaf(c0.x, xx1, t1);
        t1 = fmaf(c0.y, yy1, t1);
        t1 = fmaf(c0.z, zz1, t1);
        t1 = fmaf(c0.w, xy1, t1);
        t1 = fmaf(c1.x, xz1, t1);
        t1 = fmaf(c1.y, yz1, t1);
        t1 = fmaf(c1.z, x1,  t1);
        t1 = fmaf(c1.w, y1,  t1);
        t1 = fmaf(c2.x, z1,  t1);

        sum0 = fmaf(c2.z, fast_exp2(t0), sum0);
        sum1 = fmaf(c2.z, fast_exp2(t1), sum1);
    }

    atomicAdd(&out[i0], sum0);
    atomicAdd(&out[i1], sum1);
}

extern "C" void kernel_launch(void* const* d_in, const int* in_sizes, int n_in,
                              void* d_out, int out_size, void* d_ws, size_t ws_size,
                              hipStream_t stream) {
    const float* sample_points = (const float*)d_in[0];
    const float* positions     = (const float*)d_in[1];
    const float* scales        = (const float*)d_in[2];
    const float* rotations     = (const float*)d_in[3];
    const float* intensities   = (const float*)d_in[4];

    float* coef = (float*)d_ws;   // 4096 * 12 * 4 B = 192 KiB

    // d_out is poisoned 0xAA before every timed launch -> zero it (capture-safe)
    hipMemsetAsync(d_out, 0, (size_t)out_size * sizeof(float), stream);

    precompute_coeffs<<<N_GAUSS / 256, 256, 0, stream>>>(
        positions, scales, rotations, intensities, coef);

    gauss_eval<<<dim3(PT_BLOCKS, G_SPLIT), 256, 0, stream>>>(
        sample_points, (const float4*)coef, (float*)d_out);
}

// Round 2
// 161.733 us; speedup vs baseline: 1.0555x; 1.0555x over previous
//
#include <hip/hip_runtime.h>

// Gaussian mixture field evaluation:
//   out[m] = sum_n I_n * exp(-0.5 * (x_m - mu_n)^T A_n (x_m - mu_n))
// expanded as q = x^T A x - 2 x^T b + c with per-gaussian precomputed
// coefficients, folded with K = -0.5*log2(e) so exp(-q/2) = exp2(dot).

#define M_POINTS 65536
#define N_GAUSS  4096
#define KNEG     (-0.72134752044448170f)   // -0.5 * log2(e)

// ---------------------------------------------------------------------------
// Kernel 1: per-gaussian coefficient precompute (4096 threads) + d_out zeroing
// (fused here to drop the separate memset graph node).
// layout per gaussian (12 floats = 3 x float4):
//   [0..2]  K*a00, K*a11, K*a22
//   [3..5]  2K*a01, 2K*a02, 2K*a12
//   [6..8]  -2K*b0, -2K*b1, -2K*b2
//   [9]     K*c
//   [10]    intensity
//   [11]    pad
// ---------------------------------------------------------------------------
__global__ __launch_bounds__(256) void precompute_coeffs(
    const float* __restrict__ pos, const float* __restrict__ scl,
    const float* __restrict__ rot, const float* __restrict__ inten,
    float* __restrict__ coef, float4* __restrict__ out_zero)
{
    int n = blockIdx.x * blockDim.x + threadIdx.x;
    if (n >= N_GAUSS) return;

    // zero d_out: 65536 floats = 16384 float4 across 4096 threads
    {
        float4 z = make_float4(0.f, 0.f, 0.f, 0.f);
        out_zero[n]          = z;
        out_zero[n + 4096]   = z;
        out_zero[n + 8192]   = z;
        out_zero[n + 12288]  = z;
    }

    float qw = rot[4*n+0], qx = rot[4*n+1], qy = rot[4*n+2], qz = rot[4*n+3];
    float nrm = sqrtf(qw*qw + qx*qx + qy*qy + qz*qz) + 1e-8f;
    float ir = 1.0f / nrm;
    qw *= ir; qx *= ir; qy *= ir; qz *= ir;

    float r00 = 1.f - 2.f*(qy*qy + qz*qz);
    float r01 = 2.f*(qx*qy - qz*qw);
    float r02 = 2.f*(qx*qz + qy*qw);
    float r10 = 2.f*(qx*qy + qz*qw);
    float r11 = 1.f - 2.f*(qx*qx + qz*qz);
    float r12 = 2.f*(qy*qz - qx*qw);
    float r20 = 2.f*(qx*qz - qy*qw);
    float r21 = 2.f*(qy*qz + qx*qw);
    float r22 = 1.f - 2.f*(qx*qx + qy*qy);

    float s0 = fabsf(scl[3*n+0]) + 1e-6f;
    float s1 = fabsf(scl[3*n+1]) + 1e-6f;
    float s2 = fabsf(scl[3*n+2]) + 1e-6f;
    float w0 = 1.f/(s0*s0), w1 = 1.f/(s1*s1), w2 = 1.f/(s2*s2);

    // A = R diag(w) R^T  (symmetric)
    float a00 = r00*r00*w0 + r01*r01*w1 + r02*r02*w2;
    float a01 = r00*r10*w0 + r01*r11*w1 + r02*r12*w2;
    float a02 = r00*r20*w0 + r01*r21*w1 + r02*r22*w2;
    float a11 = r10*r10*w0 + r11*r11*w1 + r12*r12*w2;
    float a12 = r10*r20*w0 + r11*r21*w1 + r12*r22*w2;
    float a22 = r20*r20*w0 + r21*r21*w1 + r22*r22*w2;

    float p0 = pos[3*n+0], p1 = pos[3*n+1], p2 = pos[3*n+2];
    float b0 = a00*p0 + a01*p1 + a02*p2;
    float b1 = a01*p0 + a11*p1 + a12*p2;
    float b2 = a02*p0 + a12*p1 + a22*p2;
    float c  = b0*p0 + b1*p1 + b2*p2;

    float* o = coef + 12*n;
    o[0]  = KNEG * a00;
    o[1]  = KNEG * a11;
    o[2]  = KNEG * a22;
    o[3]  = 2.f * KNEG * a01;
    o[4]  = 2.f * KNEG * a02;
    o[5]  = 2.f * KNEG * a12;
    o[6]  = -2.f * KNEG * b0;
    o[7]  = -2.f * KNEG * b1;
    o[8]  = -2.f * KNEG * b2;
    o[9]  = KNEG * c;
    o[10] = inten[n];
    o[11] = 0.f;
}

__device__ __forceinline__ float fast_exp2(float x) {
#if defined(__has_builtin)
#if __has_builtin(__builtin_amdgcn_exp2f)
    return __builtin_amdgcn_exp2f(x);   // raw v_exp_f32
#else
    return exp2f(x);
#endif
#else
    return exp2f(x);
#endif
}

// ---------------------------------------------------------------------------
// Kernel 2: main evaluation.
// grid(128, 16): blockIdx.x selects a 512-point slab, blockIdx.y a
// 256-gaussian chunk. 2 points/thread (ILP-2 over the 9-deep FMA chain).
// 2048 blocks = 8 blocks/CU = 32 waves/CU -> 100% occupancy cap (VGPR=16,
// nothing else limits). Coefficient loads are wave-uniform -> s_load_dwordx4
// on the scalar pipe. Partials combined with atomicAdd (16 adds/output).
// ---------------------------------------------------------------------------
#define PT_BLOCKS 128      // 65536 / (256 threads * 2 pts)
#define G_SPLIT   16
#define G_CHUNK   (N_GAUSS / G_SPLIT)   // 256

__global__ __launch_bounds__(256) void gauss_eval(
    const float*  __restrict__ pts,
    const float4* __restrict__ coef,   // 3 x float4 per gaussian
    float*        __restrict__ out)
{
    const int t  = threadIdx.x;
    const int i0 = blockIdx.x * 512 + t;
    const int i1 = i0 + 256;

    const float x0 = pts[3*i0+0], y0 = pts[3*i0+1], z0 = pts[3*i0+2];
    const float x1 = pts[3*i1+0], y1 = pts[3*i1+1], z1 = pts[3*i1+2];

    // per-point monomials
    const float xx0 = x0*x0, yy0 = y0*y0, zz0 = z0*z0;
    const float xy0 = x0*y0, xz0 = x0*z0, yz0 = y0*z0;
    const float xx1 = x1*x1, yy1 = y1*y1, zz1 = z1*z1;
    const float xy1 = x1*y1, xz1 = x1*z1, yz1 = y1*z1;

    float sum0 = 0.f, sum1 = 0.f;

    const int nbeg = blockIdx.y * G_CHUNK;
    const int nend = nbeg + G_CHUNK;

#pragma unroll 8
    for (int n = nbeg; n < nend; ++n) {
        const float4 c0 = coef[3*n + 0];  // Ka00 Ka11 Ka22 2Ka01
        const float4 c1 = coef[3*n + 1];  // 2Ka02 2Ka12 f0 f1
        const float4 c2 = coef[3*n + 2];  // f2 Kc I pad

        float t0 = c2.y;
        t0 = fmaf(c0.x, xx0, t0);
        t0 = fmaf(c0.y, yy0, t0);
        t0 = fmaf(c0.z, zz0, t0);
        t0 = fmaf(c0.w, xy0, t0);
        t0 = fmaf(c1.x, xz0, t0);
        t0 = fmaf(c1.y, yz0, t0);
        t0 = fmaf(c1.z, x0,  t0);
        t0 = fmaf(c1.w, y0,  t0);
        t0 = fmaf(c2.x, z0,  t0);

        float t1 = c2.y;
        t1 = fmaf(c0.x, xx1, t1);
        t1 = fmaf(c0.y, yy1, t1);
        t1 = fmaf(c0.z, zz1, t1);
        t1 = fmaf(c0.w, xy1, t1);
        t1 = fmaf(c1.x, xz1, t1);
        t1 = fmaf(c1.y, yz1, t1);
        t1 = fmaf(c1.z, x1,  t1);
        t1 = fmaf(c1.w, y1,  t1);
        t1 = fmaf(c2.x, z1,  t1);

        sum0 = fmaf(c2.z, fast_exp2(t0), sum0);
        sum1 = fmaf(c2.z, fast_exp2(t1), sum1);
    }

    atomicAdd(&out[i0], sum0);
    atomicAdd(&out[i1], sum1);
}

extern "C" void kernel_launch(void* const* d_in, const int* in_sizes, int n_in,
                              void* d_out, int out_size, void* d_ws, size_t ws_size,
                              hipStream_t stream) {
    const float* sample_points = (const float*)d_in[0];
    const float* positions     = (const float*)d_in[1];
    const float* scales        = (const float*)d_in[2];
    const float* rotations     = (const float*)d_in[3];
    const float* intensities   = (const float*)d_in[4];

    float* coef = (float*)d_ws;   // 4096 * 12 * 4 B = 192 KiB

    // precompute also zeroes d_out (poisoned 0xAA before every timed launch)
    precompute_coeffs<<<N_GAUSS / 256, 256, 0, stream>>>(
        positions, scales, rotations, intensities, coef, (float4*)d_out);

    gauss_eval<<<dim3(PT_BLOCKS, G_SPLIT), 256, 0, stream>>>(
        sample_points, (const float4*)coef, (float*)d_out);
}

// Round 3
// 125.622 us; speedup vs baseline: 1.3589x; 1.2875x over previous
//
#include <hip/hip_runtime.h>

// Gaussian mixture field evaluation:
//   out[m] = sum_n I_n * exp(-0.5 * (x_m - mu_n)^T A_n (x_m - mu_n))
// expanded as q = x^T A x - 2 x^T b + c with per-gaussian precomputed
// coefficients, folded with K = -0.5*log2(e) so exp(-q/2) = exp2(dot).
//
// Round 3: VALU-issue diet. 4 points/thread, point-pairs packed as
// <2 x float> with __builtin_elementwise_fma so the backend can select
// v_pk_fma_f32 (2x FP32 FMA per issue, gfx90a+). Coefficients stay
// wave-uniform (s_load, op_sel SGPR broadcast into both pk halves).

#define M_POINTS 65536
#define N_GAUSS  4096
#define KNEG     (-0.72134752044448170f)   // -0.5 * log2(e)

typedef float v2f __attribute__((ext_vector_type(2)));

__device__ __forceinline__ v2f v2splat(float s) { v2f r; r.x = s; r.y = s; return r; }

__device__ __forceinline__ v2f vfma(v2f a, v2f b, v2f c) {
#if defined(__has_builtin)
#if __has_builtin(__builtin_elementwise_fma)
    return __builtin_elementwise_fma(a, b, c);
#else
    v2f r; r.x = fmaf(a.x, b.x, c.x); r.y = fmaf(a.y, b.y, c.y); return r;
#endif
#else
    v2f r; r.x = fmaf(a.x, b.x, c.x); r.y = fmaf(a.y, b.y, c.y); return r;
#endif
}

__device__ __forceinline__ float fast_exp2(float x) {
#if defined(__has_builtin)
#if __has_builtin(__builtin_amdgcn_exp2f)
    return __builtin_amdgcn_exp2f(x);   // raw v_exp_f32
#else
    return exp2f(x);
#endif
#else
    return exp2f(x);
#endif
}

// ---------------------------------------------------------------------------
// Kernel 1: per-gaussian coefficient precompute (4096 threads) + d_out zeroing
// layout per gaussian (12 floats = 3 x float4):
//   [0..2]  K*a00, K*a11, K*a22    [3..5] 2K*a01, 2K*a02, 2K*a12
//   [6..8]  -2K*b0, -2K*b1, -2K*b2 [9] K*c  [10] intensity  [11] pad
// ---------------------------------------------------------------------------
__global__ __launch_bounds__(256) void precompute_coeffs(
    const float* __restrict__ pos, const float* __restrict__ scl,
    const float* __restrict__ rot, const float* __restrict__ inten,
    float* __restrict__ coef, float4* __restrict__ out_zero)
{
    int n = blockIdx.x * blockDim.x + threadIdx.x;
    if (n >= N_GAUSS) return;

    // zero d_out: 65536 floats = 16384 float4 across 4096 threads
    {
        float4 z = make_float4(0.f, 0.f, 0.f, 0.f);
        out_zero[n]          = z;
        out_zero[n + 4096]   = z;
        out_zero[n + 8192]   = z;
        out_zero[n + 12288]  = z;
    }

    float qw = rot[4*n+0], qx = rot[4*n+1], qy = rot[4*n+2], qz = rot[4*n+3];
    float nrm = sqrtf(qw*qw + qx*qx + qy*qy + qz*qz) + 1e-8f;
    float ir = 1.0f / nrm;
    qw *= ir; qx *= ir; qy *= ir; qz *= ir;

    float r00 = 1.f - 2.f*(qy*qy + qz*qz);
    float r01 = 2.f*(qx*qy - qz*qw);
    float r02 = 2.f*(qx*qz + qy*qw);
    float r10 = 2.f*(qx*qy + qz*qw);
    float r11 = 1.f - 2.f*(qx*qx + qz*qz);
    float r12 = 2.f*(qy*qz - qx*qw);
    float r20 = 2.f*(qx*qz - qy*qw);
    float r21 = 2.f*(qy*qz + qx*qw);
    float r22 = 1.f - 2.f*(qx*qx + qy*qy);

    float s0 = fabsf(scl[3*n+0]) + 1e-6f;
    float s1 = fabsf(scl[3*n+1]) + 1e-6f;
    float s2 = fabsf(scl[3*n+2]) + 1e-6f;
    float w0 = 1.f/(s0*s0), w1 = 1.f/(s1*s1), w2 = 1.f/(s2*s2);

    // A = R diag(w) R^T  (symmetric)
    float a00 = r00*r00*w0 + r01*r01*w1 + r02*r02*w2;
    float a01 = r00*r10*w0 + r01*r11*w1 + r02*r12*w2;
    float a02 = r00*r20*w0 + r01*r21*w1 + r02*r22*w2;
    float a11 = r10*r10*w0 + r11*r11*w1 + r12*r12*w2;
    float a12 = r10*r20*w0 + r11*r21*w1 + r12*r22*w2;
    float a22 = r20*r20*w0 + r21*r21*w1 + r22*r22*w2;

    float p0 = pos[3*n+0], p1 = pos[3*n+1], p2 = pos[3*n+2];
    float b0 = a00*p0 + a01*p1 + a02*p2;
    float b1 = a01*p0 + a11*p1 + a12*p2;
    float b2 = a02*p0 + a12*p1 + a22*p2;
    float c  = b0*p0 + b1*p1 + b2*p2;

    float* o = coef + 12*n;
    o[0]  = KNEG * a00;
    o[1]  = KNEG * a11;
    o[2]  = KNEG * a22;
    o[3]  = 2.f * KNEG * a01;
    o[4]  = 2.f * KNEG * a02;
    o[5]  = 2.f * KNEG * a12;
    o[6]  = -2.f * KNEG * b0;
    o[7]  = -2.f * KNEG * b1;
    o[8]  = -2.f * KNEG * b2;
    o[9]  = KNEG * c;
    o[10] = inten[n];
    o[11] = 0.f;
}

// ---------------------------------------------------------------------------
// Kernel 2: main evaluation. 4 points/thread as two v2f pairs.
// grid(64, 32): bx = 1024-point slab, by = 128-gaussian chunk. 2048 blocks
// = 8 blocks/CU. Coefficients wave-uniform -> scalar loads. 32 atomic
// partials per output element.
// ---------------------------------------------------------------------------
#define PT_BLOCKS 64       // 65536 / (256 threads * 4 pts)
#define G_SPLIT   32
#define G_CHUNK   (N_GAUSS / G_SPLIT)   // 128

__global__ __launch_bounds__(256) void gauss_eval(
    const float*  __restrict__ pts,
    const float4* __restrict__ coef,   // 3 x float4 per gaussian
    float*        __restrict__ out)
{
    const int t  = threadIdx.x;
    const int i0 = blockIdx.x * 1024 + t;
    const int i1 = i0 + 256;
    const int i2 = i0 + 512;
    const int i3 = i0 + 768;

    const float x0 = pts[3*i0+0], y0 = pts[3*i0+1], z0 = pts[3*i0+2];
    const float x1 = pts[3*i1+0], y1 = pts[3*i1+1], z1 = pts[3*i1+2];
    const float x2 = pts[3*i2+0], y2 = pts[3*i2+1], z2 = pts[3*i2+2];
    const float x3 = pts[3*i3+0], y3 = pts[3*i3+1], z3 = pts[3*i3+2];

    // monomial pairs: A = points (0,1), B = points (2,3)
    v2f xA = {x0, x1}, yA = {y0, y1}, zA = {z0, z1};
    v2f xB = {x2, x3}, yB = {y2, y3}, zB = {z2, z3};
    v2f xxA = xA*xA, yyA = yA*yA, zzA = zA*zA;
    v2f xyA = xA*yA, xzA = xA*zA, yzA = yA*zA;
    v2f xxB = xB*xB, yyB = yB*yB, zzB = zB*zB;
    v2f xyB = xB*yB, xzB = xB*zB, yzB = yB*zB;

    v2f sumA = {0.f, 0.f}, sumB = {0.f, 0.f};

    const int nbeg = blockIdx.y * G_CHUNK;
    const int nend = nbeg + G_CHUNK;

#pragma unroll 4
    for (int n = nbeg; n < nend; ++n) {
        const float4 c0 = coef[3*n + 0];  // Ka00 Ka11 Ka22 2Ka01
        const float4 c1 = coef[3*n + 1];  // 2Ka02 2Ka12 f0 f1
        const float4 c2 = coef[3*n + 2];  // f2 Kc I pad

        v2f tA = v2splat(c2.y);
        v2f tB = tA;
        tA = vfma(v2splat(c0.x), xxA, tA);  tB = vfma(v2splat(c0.x), xxB, tB);
        tA = vfma(v2splat(c0.y), yyA, tA);  tB = vfma(v2splat(c0.y), yyB, tB);
        tA = vfma(v2splat(c0.z), zzA, tA);  tB = vfma(v2splat(c0.z), zzB, tB);
        tA = vfma(v2splat(c0.w), xyA, tA);  tB = vfma(v2splat(c0.w), xyB, tB);
        tA = vfma(v2splat(c1.x), xzA, tA);  tB = vfma(v2splat(c1.x), xzB, tB);
        tA = vfma(v2splat(c1.y), yzA, tA);  tB = vfma(v2splat(c1.y), yzB, tB);
        tA = vfma(v2splat(c1.z), xA,  tA);  tB = vfma(v2splat(c1.z), xB,  tB);
        tA = vfma(v2splat(c1.w), yA,  tA);  tB = vfma(v2splat(c1.w), yB,  tB);
        tA = vfma(v2splat(c2.x), zA,  tA);  tB = vfma(v2splat(c2.x), zB,  tB);

        v2f eA, eB;
        eA.x = fast_exp2(tA.x);  eA.y = fast_exp2(tA.y);
        eB.x = fast_exp2(tB.x);  eB.y = fast_exp2(tB.y);

        v2f vi = v2splat(c2.z);
        sumA = vfma(vi, eA, sumA);
        sumB = vfma(vi, eB, sumB);
    }

    atomicAdd(&out[i0], sumA.x);
    atomicAdd(&out[i1], sumA.y);
    atomicAdd(&out[i2], sumB.x);
    atomicAdd(&out[i3], sumB.y);
}

extern "C" void kernel_launch(void* const* d_in, const int* in_sizes, int n_in,
                              void* d_out, int out_size, void* d_ws, size_t ws_size,
                              hipStream_t stream) {
    const float* sample_points = (const float*)d_in[0];
    const float* positions     = (const float*)d_in[1];
    const float* scales        = (const float*)d_in[2];
    const float* rotations     = (const float*)d_in[3];
    const float* intensities   = (const float*)d_in[4];

    float* coef = (float*)d_ws;   // 4096 * 12 * 4 B = 192 KiB

    // precompute also zeroes d_out (poisoned 0xAA before every timed launch)
    precompute_coeffs<<<N_GAUSS / 256, 256, 0, stream>>>(
        positions, scales, rotations, intensities, coef, (float4*)d_out);

    gauss_eval<<<dim3(PT_BLOCKS, G_SPLIT), 256, 0, stream>>>(
        sample_points, (const float4*)coef, (float*)d_out);
}

// Round 4
// 110.272 us; speedup vs baseline: 1.5481x; 1.1392x over previous
//
#include <hip/hip_runtime.h>

// Gaussian mixture field evaluation via MFMA:
//   out[m] = sum_n exp2( K*q[m,n] + log2(I_n) ),  K = -0.5*log2(e)
//   q[m,n] = x^T A_n x - 2 x^T b_n + c_n  ==  dot(P[m][0..9], C[n][0..9])
// P = {x^2,y^2,z^2,xy,xz,yz,x,y,z,1}, C = {Ka00,Ka11,Ka22,2Ka01,2Ka02,2Ka12,
//      -2Kb0,-2Kb1,-2Kb2, Kc+log2(I)}.
// Both sides split fp32 -> f16 hi+lo; products hi*hi + lo*hi + hi*lo (drop
// lo*lo) -> 30 K-slots -> ONE v_mfma_f32_16x16x32_f16 per 16x16 q-tile.
// k-order: k=3j -> (A:phi_j, B:chi_j); 3j+1 -> (A:plo_j, B:chi_j);
//          3j+2 -> (A:phi_j, B:clo_j); k=30,31 zero.
//
// Verified gfx950 layouts (learn_hip m89/m91):
//   A-frag: lane holds A[m=lane&15][k=(lane>>4)*8+j], j=0..7
//   B-frag: lane holds B[k=(lane>>4)*8+j][n=lane&15]
//   D:      lane holds D[row=(lane>>4)*4+r][col=lane&15], r=0..3

#define M_POINTS 65536
#define N_GAUSS  4096
#define KNEG     (-0.72134752044448170f)   // -0.5 * log2(e)

typedef _Float16 half8  __attribute__((ext_vector_type(8)));
typedef float    float4v __attribute__((ext_vector_type(4)));

__device__ __forceinline__ float fast_exp2(float x) {
#if defined(__has_builtin)
#if __has_builtin(__builtin_amdgcn_exp2f)
    return __builtin_amdgcn_exp2f(x);   // raw v_exp_f32
#else
    return exp2f(x);
#endif
#else
    return exp2f(x);
#endif
}

// ---------------------------------------------------------------------------
// Kernel 1: per-gaussian coefficient precompute, written directly in MFMA
// B-operand fragment layout: bfrag[tile*64 + lane] = half8 for that lane.
// 256 tiles * 64 lanes * 16 B = 256 KiB in d_ws.
// ---------------------------------------------------------------------------
__global__ __launch_bounds__(64) void precompute_bfrag(
    const float* __restrict__ pos, const float* __restrict__ scl,
    const float* __restrict__ rot, const float* __restrict__ inten,
    half8* __restrict__ bfrag)
{
    int n = blockIdx.x * 64 + threadIdx.x;
    if (n >= N_GAUSS) return;

    float qw = rot[4*n+0], qx = rot[4*n+1], qy = rot[4*n+2], qz = rot[4*n+3];
    float nrm = sqrtf(qw*qw + qx*qx + qy*qy + qz*qz) + 1e-8f;
    float ir = 1.0f / nrm;
    qw *= ir; qx *= ir; qy *= ir; qz *= ir;

    float r00 = 1.f - 2.f*(qy*qy + qz*qz);
    float r01 = 2.f*(qx*qy - qz*qw);
    float r02 = 2.f*(qx*qz + qy*qw);
    float r10 = 2.f*(qx*qy + qz*qw);
    float r11 = 1.f - 2.f*(qx*qx + qz*qz);
    float r12 = 2.f*(qy*qz - qx*qw);
    float r20 = 2.f*(qx*qz - qy*qw);
    float r21 = 2.f*(qy*qz + qx*qw);
    float r22 = 1.f - 2.f*(qx*qx + qy*qy);

    float s0 = fabsf(scl[3*n+0]) + 1e-6f;
    float s1 = fabsf(scl[3*n+1]) + 1e-6f;
    float s2 = fabsf(scl[3*n+2]) + 1e-6f;
    float w0 = 1.f/(s0*s0), w1 = 1.f/(s1*s1), w2 = 1.f/(s2*s2);

    float a00 = r00*r00*w0 + r01*r01*w1 + r02*r02*w2;
    float a01 = r00*r10*w0 + r01*r11*w1 + r02*r12*w2;
    float a02 = r00*r20*w0 + r01*r21*w1 + r02*r22*w2;
    float a11 = r10*r10*w0 + r11*r11*w1 + r12*r12*w2;
    float a12 = r10*r20*w0 + r11*r21*w1 + r12*r22*w2;
    float a22 = r20*r20*w0 + r21*r21*w1 + r22*r22*w2;

    float p0 = pos[3*n+0], p1 = pos[3*n+1], p2 = pos[3*n+2];
    float b0 = a00*p0 + a01*p1 + a02*p2;
    float b1 = a01*p0 + a11*p1 + a12*p2;
    float b2 = a02*p0 + a12*p1 + a22*p2;
    float c  = b0*p0 + b1*p1 + b2*p2;

    float I = fmaxf(inten[n], 1e-30f);   // I=0 -> t=-100ish -> exp2 -> 0

    float C[10];
    C[0] = KNEG * a00;       C[1] = KNEG * a11;       C[2] = KNEG * a22;
    C[3] = 2.f*KNEG * a01;   C[4] = 2.f*KNEG * a02;   C[5] = 2.f*KNEG * a12;
    C[6] = -2.f*KNEG * b0;   C[7] = -2.f*KNEG * b1;   C[8] = -2.f*KNEG * b2;
    C[9] = KNEG * c + log2f(I);

    _Float16 chi[10], clo[10];
#pragma unroll
    for (int j = 0; j < 10; ++j) {
        chi[j] = (_Float16)C[j];
        clo[j] = (_Float16)(C[j] - (float)chi[j]);
    }

    const int tile = n >> 4, nl = n & 15;
#pragma unroll
    for (int q = 0; q < 4; ++q) {
        half8 v;
#pragma unroll
        for (int j = 0; j < 8; ++j) {
            const int k = q*8 + j;
            _Float16 h = (_Float16)0.f;
            if (k < 30) {
                const int jm = k / 3, s = k % 3;
                h = (s == 2) ? clo[jm] : chi[jm];
            }
            v[j] = h;
        }
        bfrag[tile*64 + q*16 + nl] = v;
    }
}

// ---------------------------------------------------------------------------
// Kernel 2: main evaluation. 1024 blocks x 256 threads (4 waves). Each wave
// owns one 16-point tile (A-frag built once, in registers) and sweeps all 256
// gaussian tiles. B-frags double-buffered through LDS in rounds of 16 tiles
// (32 KiB). Epilogue: acc += exp2(d) per D-reg, shuffle-reduce over the 16
// gaussian lanes, direct float4 store (no atomics, full overwrite of d_out).
// ---------------------------------------------------------------------------
__global__ __launch_bounds__(256) void gauss_eval(
    const float* __restrict__ pts,
    const half8* __restrict__ bfrag,
    float* __restrict__ out)
{
    __shared__ half8 lds[2 * 16 * 64];   // 2 bufs x 16 tiles x 64 lanes = 32 KiB

    const int tid  = threadIdx.x;
    const int lane = tid & 63;
    const int wv   = tid >> 6;
    const int ml   = lane & 15;          // A-operand m index / B n index
    const int q    = lane >> 4;          // quad -> k group / D row group

    // ---- build A-frag for this wave's point tile (one-time) ----
    const int ptbase = blockIdx.x * 64 + wv * 16;
    const int pt = ptbase + ml;
    const float x = pts[3*pt+0], y = pts[3*pt+1], z = pts[3*pt+2];
    const float P[10] = {x*x, y*y, z*z, x*y, x*z, y*z, x, y, z, 1.f};

    _Float16 v[32];
#pragma unroll
    for (int j = 0; j < 10; ++j) {
        _Float16 hi = (_Float16)P[j];
        _Float16 lo = (_Float16)(P[j] - (float)hi);
        v[3*j]   = hi;   // pairs with chi
        v[3*j+1] = lo;   // pairs with chi
        v[3*j+2] = hi;   // pairs with clo
    }
    v[30] = (_Float16)0.f; v[31] = (_Float16)0.f;

    half8 afrag;
#pragma unroll
    for (int j = 0; j < 8; ++j) {
        _Float16 lo01 = (q & 1) ? v[8 + j]  : v[j];
        _Float16 hi23 = (q & 1) ? v[24 + j] : v[16 + j];
        afrag[j] = (q & 2) ? hi23 : lo01;
    }

    float acc0 = 0.f, acc1 = 0.f, acc2 = 0.f, acc3 = 0.f;
    const float4v zero4 = {0.f, 0.f, 0.f, 0.f};

    // ---- stage round 0 (each wave: 4 tiles, coalesced 16 B/lane) ----
    {
        const half8* src = bfrag + (0 + wv*4) * 64;
        half8* dst = lds + (wv*4) * 64;
#pragma unroll
        for (int i = 0; i < 4; ++i) dst[i*64 + lane] = src[i*64 + lane];
    }
    __syncthreads();

    for (int r = 0; r < 16; ++r) {
        const half8* cur = lds + (r & 1) * 1024;
        half8* nxt       = lds + ((r + 1) & 1) * 1024;

        if (r < 15) {   // prefetch next round into the other buffer
            const half8* src = bfrag + ((r+1)*16 + wv*4) * 64;
            half8* dst = nxt + (wv*4) * 64;
#pragma unroll
            for (int i = 0; i < 4; ++i) dst[i*64 + lane] = src[i*64 + lane];
        }

#pragma unroll
        for (int i = 0; i < 16; ++i) {
            half8 b = cur[i*64 + lane];
            float4v d = __builtin_amdgcn_mfma_f32_16x16x32_f16(afrag, b, zero4, 0, 0, 0);
            acc0 += fast_exp2(d[0]);
            acc1 += fast_exp2(d[1]);
            acc2 += fast_exp2(d[2]);
            acc3 += fast_exp2(d[3]);
        }
        __syncthreads();
    }

    // ---- reduce over the 16 gaussian lanes within each quad ----
#pragma unroll
    for (int m = 1; m <= 8; m <<= 1) {
        acc0 += __shfl_xor(acc0, m);
        acc1 += __shfl_xor(acc1, m);
        acc2 += __shfl_xor(acc2, m);
        acc3 += __shfl_xor(acc3, m);
    }

    // lane ml==0 of each quad holds sums for points ptbase + q*4 + {0..3}
    if (ml == 0) {
        float4 o;
        o.x = acc0; o.y = acc1; o.z = acc2; o.w = acc3;
        *(float4*)(out + ptbase + q*4) = o;
    }
}

extern "C" void kernel_launch(void* const* d_in, const int* in_sizes, int n_in,
                              void* d_out, int out_size, void* d_ws, size_t ws_size,
                              hipStream_t stream) {
    const float* sample_points = (const float*)d_in[0];
    const float* positions     = (const float*)d_in[1];
    const float* scales        = (const float*)d_in[2];
    const float* rotations     = (const float*)d_in[3];
    const float* intensities   = (const float*)d_in[4];

    half8* bfrag = (half8*)d_ws;   // 256 KiB

    precompute_bfrag<<<N_GAUSS / 64, 64, 0, stream>>>(
        positions, scales, rotations, intensities, bfrag);

    gauss_eval<<<M_POINTS / 64, 256, 0, stream>>>(
        sample_points, bfrag, (float*)d_out);
}